// Round 4
// baseline (641.946 us; speedup 1.0000x reference)
//
#include <hip/hip_runtime.h>

#define LOG2E 1.4426950408889634f

__device__ __forceinline__ float fast_sig(float x) {
  return __builtin_amdgcn_rcpf(1.0f + __builtin_amdgcn_exp2f(-x * LOG2E));
}
__device__ __forceinline__ float fast_tanh(float x) {
  float e = __builtin_amdgcn_exp2f(x * (2.0f * LOG2E));
  return 1.0f - 2.0f * __builtin_amdgcn_rcpf(e + 1.0f);
}

// 128 encoder W_hh weights as NAMED SCALARS (no aggregate -> nothing for the
// compiler to demote to scratch; rounds 1-3 pathology was the whh[4][32]
// array living in scratch: VGPR_Count=84, ~3x instruction count).
#define DECLW(g) float w##g##_0,w##g##_1,w##g##_2,w##g##_3,w##g##_4,w##g##_5,w##g##_6,w##g##_7, \
  w##g##_8,w##g##_9,w##g##_10,w##g##_11,w##g##_12,w##g##_13,w##g##_14,w##g##_15, \
  w##g##_16,w##g##_17,w##g##_18,w##g##_19,w##g##_20,w##g##_21,w##g##_22,w##g##_23, \
  w##g##_24,w##g##_25,w##g##_26,w##g##_27,w##g##_28,w##g##_29,w##g##_30,w##g##_31;

#define LDQ(g,q,i0,i1,i2,i3) { float4 t = wrow##g[q]; \
  w##g##_##i0 = t.x; w##g##_##i1 = t.y; w##g##_##i2 = t.z; w##g##_##i3 = t.w; }
#define LDW(g) { const float4* wrow##g = (const float4*)(eWhh + ((g)*32 + lane)*32); \
  LDQ(g,0,0,1,2,3) LDQ(g,1,4,5,6,7) LDQ(g,2,8,9,10,11) LDQ(g,3,12,13,14,15) \
  LDQ(g,4,16,17,18,19) LDQ(g,5,20,21,22,23) LDQ(g,6,24,25,26,27) LDQ(g,7,28,29,30,31) }

#define PIN8(g,i0,i1,i2,i3,i4,i5,i6,i7) \
  asm volatile("" : "+v"(w##g##_##i0), "+v"(w##g##_##i1), "+v"(w##g##_##i2), "+v"(w##g##_##i3), \
                    "+v"(w##g##_##i4), "+v"(w##g##_##i5), "+v"(w##g##_##i6), "+v"(w##g##_##i7));
#define PINW(g) PIN8(g,0,1,2,3,4,5,6,7) PIN8(g,8,9,10,11,12,13,14,15) \
  PIN8(g,16,17,18,19,20,21,22,23) PIN8(g,24,25,26,27,28,29,30,31)

// one k-term of the recurrence GEMV: broadcast h_k from lane k of the 32-lane
// group (ds_swizzle BitMode or_mask=k), 4 FMAs against this lane's 4 gate rows
#define KS(k) { float hk = __int_as_float(__builtin_amdgcn_ds_swizzle(hb, (k) << 5)); \
  a0 = fmaf(w0_##k, hk, a0); a1 = fmaf(w1_##k, hk, a1);                               \
  a2 = fmaf(w2_##k, hk, a2); a3 = fmaf(w3_##k, hk, a3); }

#define STEP(xt) {                                                                    \
  float a0 = fmaf(wih0, (xt), bb0);                                                   \
  float a1 = fmaf(wih1, (xt), bb1);                                                   \
  float a2 = fmaf(wih2, (xt), bb2);                                                   \
  float a3 = fmaf(wih3, (xt), bb3);                                                   \
  int hb = __float_as_int(h);                                                         \
  KS(0)  KS(1)  KS(2)  KS(3)  KS(4)  KS(5)  KS(6)  KS(7)                              \
  KS(8)  KS(9)  KS(10) KS(11) KS(12) KS(13) KS(14) KS(15)                             \
  KS(16) KS(17) KS(18) KS(19) KS(20) KS(21) KS(22) KS(23)                             \
  KS(24) KS(25) KS(26) KS(27) KS(28) KS(29) KS(30) KS(31)                             \
  float ig = fast_sig(a0);                                                            \
  float fg = fast_sig(a1);                                                            \
  float gg = fast_tanh(a2);                                                           \
  float og = fast_sig(a3);                                                            \
  c = fmaf(fg, c, ig * gg);                                                           \
  h = og * fast_tanh(c);                                                              \
}

__global__ __launch_bounds__(256, 2) void lstm_ae_kernel(
    const float* __restrict__ x,
    const float* __restrict__ eWih, const float* __restrict__ eWhh,
    const float* __restrict__ eBih, const float* __restrict__ eBhh,
    const float* __restrict__ dWih, const float* __restrict__ dWhh,
    const float* __restrict__ dBih, const float* __restrict__ dBhh,
    float* __restrict__ out, int B)
{
  __shared__ __align__(16) float xsh[8 * 256];
  const int tid  = threadIdx.x;
  const int grp  = tid >> 5;
  const int lane = tid & 31;
  const int b    = blockIdx.x * 8 + grp;

  // ---- stage 8 x-rows into LDS, coalesced float4 ----
  {
    const int baseF = blockIdx.x * 8 * 256;
    const float4* src = (const float4*)(x + baseF);
    float4* dst = (float4*)xsh;
    #pragma unroll
    for (int v = 0; v < 2; ++v) {
      int idx = tid + v * 256;
      if (baseF + idx * 4 < B * 256) dst[idx] = src[idx];
    }
  }
  __syncthreads();
  if (b >= B) return;

  // ---- encoder weights: lane owns hidden unit `lane`; 4 gate rows ----
  DECLW(0) DECLW(1) DECLW(2) DECLW(3)
  LDW(0) LDW(1) LDW(2) LDW(3)
  float wih0 = eWih[lane],      wih1 = eWih[32 + lane],
        wih2 = eWih[64 + lane], wih3 = eWih[96 + lane];
  float bb0 = eBih[lane]      + eBhh[lane];
  float bb1 = eBih[32 + lane] + eBhh[32 + lane];
  float bb2 = eBih[64 + lane] + eBhh[64 + lane];
  float bb3 = eBih[96 + lane] + eBhh[96 + lane];
  PINW(0) PINW(1) PINW(2) PINW(3)
  asm volatile("" : "+v"(wih0), "+v"(wih1), "+v"(wih2), "+v"(wih3),
                    "+v"(bb0), "+v"(bb1), "+v"(bb2), "+v"(bb3));

  // ---- encoder recurrence ----
  float h = 0.0f, c = 0.0f;
  const float4* xr4 = (const float4*)(&xsh[grp * 256]);
  for (int t4 = 0; t4 < 64; ++t4) {
    float4 xv = xr4[t4];
    STEP(xv.x) STEP(xv.y) STEP(xv.z) STEP(xv.w)
  }

  // ---- decoder x-gates: 32-lane reduce of dWih[g][:]*h ----
  float p0 = dWih[0 * 32 + lane] * h;
  float p1 = dWih[1 * 32 + lane] * h;
  float p2 = dWih[2 * 32 + lane] * h;
  float p3 = dWih[3 * 32 + lane] * h;
  #define RD(m) {                                                                           \
    p0 += __int_as_float(__builtin_amdgcn_ds_swizzle(__float_as_int(p0), ((m)<<10)|0x1F)); \
    p1 += __int_as_float(__builtin_amdgcn_ds_swizzle(__float_as_int(p1), ((m)<<10)|0x1F)); \
    p2 += __int_as_float(__builtin_amdgcn_ds_swizzle(__float_as_int(p2), ((m)<<10)|0x1F)); \
    p3 += __int_as_float(__builtin_amdgcn_ds_swizzle(__float_as_int(p3), ((m)<<10)|0x1F)); }
  RD(1) RD(2) RD(4) RD(8) RD(16)
  #undef RD
  const float xg0 = p0 + dBih[0] + dBhh[0];
  const float xg1 = p1 + dBih[1] + dBhh[1];
  const float xg2 = p2 + dBih[2] + dBhh[2];
  const float xg3 = p3 + dBih[3] + dBhh[3];
  const float w0 = dWhh[0], w1 = dWhh[1], w2 = dWhh[2], w3 = dWhh[3];

  // ---- decoder recurrence (redundant across lanes; coalesced stores) ----
  float hd = 0.0f, cd = 0.0f;
  float* op = out + (size_t)b * 256;
  for (int j = 0; j < 8; ++j) {
    float ob = 0.0f;
    #pragma unroll
    for (int l = 0; l < 32; ++l) {
      float g0 = fmaf(w0, hd, xg0);
      float g1 = fmaf(w1, hd, xg1);
      float g2 = fmaf(w2, hd, xg2);
      float g3 = fmaf(w3, hd, xg3);
      float ii = fast_sig(g0);
      float ff = fast_sig(g1);
      float gg = fast_tanh(g2);
      float oo = fast_sig(g3);
      cd = fmaf(ff, cd, ii * gg);
      hd = oo * fast_tanh(cd);
      ob = (lane == l) ? hd : ob;
    }
    op[j * 32 + lane] = ob;
  }
}

extern "C" void kernel_launch(void* const* d_in, const int* in_sizes, int n_in,
                              void* d_out, int out_size, void* d_ws, size_t ws_size,
                              hipStream_t stream) {
  const float* x    = (const float*)d_in[0];
  const float* eWih = (const float*)d_in[1];
  const float* eWhh = (const float*)d_in[2];
  const float* eBih = (const float*)d_in[3];
  const float* eBhh = (const float*)d_in[4];
  const float* dWih = (const float*)d_in[5];
  const float* dWhh = (const float*)d_in[6];
  const float* dBih = (const float*)d_in[7];
  const float* dBhh = (const float*)d_in[8];
  float* out = (float*)d_out;

  const int B = out_size / 256;          // T = 256, output [B, T, 1]
  const int grid = (B + 7) / 8;          // 8 elements per 256-thread block
  lstm_ae_kernel<<<grid, 256, 0, stream>>>(x, eWih, eWhh, eBih, eBhh,
                                           dWih, dWhh, dBih, dBhh, out, B);
}

// Round 14
// 290.402 us; speedup vs baseline: 2.2105x; 2.2105x over previous
//
#include <hip/hip_runtime.h>

#define LOG2E 1.4426950408889634f

typedef float v2f __attribute__((ext_vector_type(2)));

__device__ __forceinline__ float fast_sig(float x) {
  return __builtin_amdgcn_rcpf(1.0f + __builtin_amdgcn_exp2f(-x * LOG2E));
}
__device__ __forceinline__ float fast_tanh(float x) {
  float e = __builtin_amdgcn_exp2f(x * (2.0f * LOG2E));
  return 1.0f - 2.0f * __builtin_amdgcn_rcpf(e + 1.0f);
}

__device__ __forceinline__ v2f vfma(v2f a, v2f b, v2f c) {
#if __has_builtin(__builtin_elementwise_fma)
  return __builtin_elementwise_fma(a, b, c);   // -> v_pk_fma_f32 on gfx950
#else
  v2f r; r.x = fmaf(a.x, b.x, c.x); r.y = fmaf(a.y, b.y, c.y); return r;
#endif
}

// ---- 64 packed weight pairs as NAMED scalars (no aggregates -> no scratch) --
#define D8(P,i0,i1,i2,i3,i4,i5,i6,i7) v2f P##i0,P##i1,P##i2,P##i3,P##i4,P##i5,P##i6,P##i7;
#define DECLP(P) D8(P,0,1,2,3,4,5,6,7) D8(P,8,9,10,11,12,13,14,15) \
                 D8(P,16,17,18,19,20,21,22,23) D8(P,24,25,26,27,28,29,30,31)

#define L1(P,ra,rb,k) P##k = (v2f){(ra)[k], (rb)[k]};
#define L8(P,ra,rb,i0,i1,i2,i3,i4,i5,i6,i7) L1(P,ra,rb,i0) L1(P,ra,rb,i1) L1(P,ra,rb,i2) \
  L1(P,ra,rb,i3) L1(P,ra,rb,i4) L1(P,ra,rb,i5) L1(P,ra,rb,i6) L1(P,ra,rb,i7)
#define LOADP(P,ra,rb) L8(P,ra,rb,0,1,2,3,4,5,6,7) L8(P,ra,rb,8,9,10,11,12,13,14,15) \
  L8(P,ra,rb,16,17,18,19,20,21,22,23) L8(P,ra,rb,24,25,26,27,28,29,30,31)

// one k-term: broadcast h_k within the 32-lane group, 2 packed FMAs = 4 MACs
#define KS(k) { float hk = __int_as_float(__builtin_amdgcn_ds_swizzle(hb, (k) << 5)); \
  v2f _hv; _hv.x = hk; _hv.y = hk;                                                    \
  A01 = vfma(P01_##k, _hv, A01); A23 = vfma(P23_##k, _hv, A23); }

#define STEP(xt) {                                                                    \
  v2f _xpk; _xpk.x = (xt); _xpk.y = (xt);                                             \
  v2f A01 = vfma(WIH01, _xpk, BB01);                                                  \
  v2f A23 = vfma(WIH23, _xpk, BB23);                                                  \
  int hb = __float_as_int(h);                                                         \
  KS(0)  KS(1)  KS(2)  KS(3)  KS(4)  KS(5)  KS(6)  KS(7)                              \
  KS(8)  KS(9)  KS(10) KS(11) KS(12) KS(13) KS(14) KS(15)                             \
  KS(16) KS(17) KS(18) KS(19) KS(20) KS(21) KS(22) KS(23)                             \
  KS(24) KS(25) KS(26) KS(27) KS(28) KS(29) KS(30) KS(31)                             \
  float ig = fast_sig(A01.x);                                                         \
  float fg = fast_sig(A01.y);                                                         \
  float gg = fast_tanh(A23.x);                                                        \
  float og = fast_sig(A23.y);                                                         \
  c = fmaf(fg, c, ig * gg);                                                           \
  h = og * fast_tanh(c);                                                              \
}

// ===================== kernel 1: encoder + decoder x-gates ===================
__global__ __launch_bounds__(256)
__attribute__((amdgpu_waves_per_eu(1, 2)))        // max 2 waves/EU: 256-VGPR budget,
void enc_kernel(                                  // stops occupancy-seeking spills
    const float* __restrict__ x,
    const float* __restrict__ eWih, const float* __restrict__ eWhh,
    const float* __restrict__ eBih, const float* __restrict__ eBhh,
    const float* __restrict__ dWih,
    const float* __restrict__ dBih, const float* __restrict__ dBhh,
    float* __restrict__ xg_out, int B)
{
  __shared__ __align__(16) float xsh[8 * 256];
  const int tid  = threadIdx.x;
  const int grp  = tid >> 5;
  const int lane = tid & 31;
  const int b    = blockIdx.x * 8 + grp;

  // stage 8 x-rows into LDS (coalesced float4)
  {
    const int baseF = blockIdx.x * 8 * 256;
    const float4* src = (const float4*)(x + baseF);
    float4* dst = (float4*)xsh;
    #pragma unroll
    for (int v = 0; v < 2; ++v) {
      int idx = tid + v * 256;
      if (baseF + idx * 4 < B * 256) dst[idx] = src[idx];
    }
  }
  __syncthreads();

  // encoder weights: lane owns hidden unit `lane`.
  // P01_k = (W_i[lane][k], W_f[lane][k]); P23_k = (W_g[lane][k], W_o[lane][k]).
  DECLP(P01_) DECLP(P23_)
  {
    const float* ri = eWhh + (0 * 32 + lane) * 32;
    const float* rf = eWhh + (1 * 32 + lane) * 32;
    LOADP(P01_, ri, rf)
  }
  {
    const float* rg = eWhh + (2 * 32 + lane) * 32;
    const float* ro = eWhh + (3 * 32 + lane) * 32;
    LOADP(P23_, rg, ro)
  }
  v2f WIH01 = (v2f){eWih[lane],        eWih[32 + lane]};
  v2f WIH23 = (v2f){eWih[64 + lane],   eWih[96 + lane]};
  v2f BB01  = (v2f){eBih[lane]      + eBhh[lane],
                    eBih[32 + lane] + eBhh[32 + lane]};
  v2f BB23  = (v2f){eBih[64 + lane] + eBhh[64 + lane],
                    eBih[96 + lane] + eBhh[96 + lane]};

  // encoder recurrence (unroll 1: keep code size small -- container disk is
  // tight; body already has 8 independent packed-FMA chains for ILP)
  float h = 0.0f, c = 0.0f;
  const float4* xr4 = (const float4*)(&xsh[grp * 256]);
  #pragma unroll 1
  for (int t4 = 0; t4 < 64; ++t4) {
    float4 xv = xr4[t4];
    STEP(xv.x) STEP(xv.y) STEP(xv.z) STEP(xv.w)
  }

  // decoder x-gates: xg[g] = sum_u dWih[g][u]*h_u + dBih[g]+dBhh[g]
  float p0 = dWih[0 * 32 + lane] * h;
  float p1 = dWih[1 * 32 + lane] * h;
  float p2 = dWih[2 * 32 + lane] * h;
  float p3 = dWih[3 * 32 + lane] * h;
  #define RD(m) {                                                                           \
    p0 += __int_as_float(__builtin_amdgcn_ds_swizzle(__float_as_int(p0), ((m)<<10)|0x1F)); \
    p1 += __int_as_float(__builtin_amdgcn_ds_swizzle(__float_as_int(p1), ((m)<<10)|0x1F)); \
    p2 += __int_as_float(__builtin_amdgcn_ds_swizzle(__float_as_int(p2), ((m)<<10)|0x1F)); \
    p3 += __int_as_float(__builtin_amdgcn_ds_swizzle(__float_as_int(p3), ((m)<<10)|0x1F)); }
  RD(1) RD(2) RD(4) RD(8) RD(16)
  #undef RD

  if (lane == 0 && b < B) {
    float4 xg;
    xg.x = p0 + dBih[0] + dBhh[0];
    xg.y = p1 + dBih[1] + dBhh[1];
    xg.z = p2 + dBih[2] + dBhh[2];
    xg.w = p3 + dBih[3] + dBhh[3];
    ((float4*)xg_out)[b] = xg;
  }
}

// ===================== kernel 2: decoder, one element per LANE ===============
__global__ __launch_bounds__(64) void dec_kernel(
    const float* __restrict__ xg_in, const float* __restrict__ dWhh,
    float* __restrict__ out, int B)
{
  const int e = blockIdx.x * 64 + threadIdx.x;
  if (e >= B) return;
  const float4 xg = ((const float4*)xg_in)[e];
  const float w0 = dWhh[0], w1 = dWhh[1], w2 = dWhh[2], w3 = dWhh[3];

  float hd = 0.0f, cd = 0.0f;
  float4* op = (float4*)(out + (size_t)e * 256);
  #pragma unroll 1
  for (int j = 0; j < 64; ++j) {
    float4 ob;
    #pragma unroll
    for (int q = 0; q < 4; ++q) {
      float g0 = fmaf(w0, hd, xg.x);
      float g1 = fmaf(w1, hd, xg.y);
      float g2 = fmaf(w2, hd, xg.z);
      float g3 = fmaf(w3, hd, xg.w);
      float ii = fast_sig(g0);
      float ff = fast_sig(g1);
      float gg = fast_tanh(g2);
      float oo = fast_sig(g3);
      cd = fmaf(ff, cd, ii * gg);
      hd = oo * fast_tanh(cd);
      ((float*)&ob)[q] = hd;
    }
    op[j] = ob;
  }
}

extern "C" void kernel_launch(void* const* d_in, const int* in_sizes, int n_in,
                              void* d_out, int out_size, void* d_ws, size_t ws_size,
                              hipStream_t stream) {
  const float* x    = (const float*)d_in[0];
  const float* eWih = (const float*)d_in[1];
  const float* eWhh = (const float*)d_in[2];
  const float* eBih = (const float*)d_in[3];
  const float* eBhh = (const float*)d_in[4];
  const float* dWih = (const float*)d_in[5];
  const float* dWhh = (const float*)d_in[6];
  const float* dBih = (const float*)d_in[7];
  const float* dBhh = (const float*)d_in[8];
  float* out = (float*)d_out;
  float* xg  = (float*)d_ws;                 // B * 4 floats = 128 KiB scratch

  const int B = out_size / 256;              // T = 256, output [B, T, 1]
  enc_kernel<<<(B + 7) / 8, 256, 0, stream>>>(x, eWih, eWhh, eBih, eBhh,
                                              dWih, dBih, dBhh, xg, B);
  dec_kernel<<<(B + 63) / 64, 64, 0, stream>>>(xg, dWhh, out, B);
}